// Round 1
// baseline (44.350 us; speedup 1.0000x reference)
//
#include <hip/hip_runtime.h>

#define BLOCK 256
#define NPT 4                     // nodes per thread
#define CHUNK (BLOCK * NPT)       // 1024 nodes per block
#define TBL 64                    // LDS segment table entries per block

__global__ __launch_bounds__(BLOCK) void e3nn_fused(
    const int* __restrict__ z, const float* __restrict__ pos,
    const int* __restrict__ batch,
    const float* __restrict__ embed,
    const float* __restrict__ lin_w, const float* __restrict__ lin_b,
    const float* __restrict__ tp1_w, const float* __restrict__ tp2_w,
    const float* __restrict__ tp3_w, const float* __restrict__ gate_w,
    const float* __restrict__ fc_w, const float* __restrict__ fc_b,
    float* __restrict__ out, int n)
{
    __shared__ float acc[TBL * 3];
    __shared__ int s_bfirst;

    const int tid = threadIdx.x;
    const long long chunk0 = (long long)blockIdx.x * CHUNK;

    for (int i = tid; i < TBL * 3; i += BLOCK) acc[i] = 0.0f;
    if (tid == 0) s_bfirst = batch[chunk0];
    __syncthreads();
    const int bfirst = s_bfirst;

    // Wigner / path-weight constants
    const float C01 = 0.57735026918962576f;   // 1/sqrt(3)
    const float C11 = 0.40824829046386302f;   // 1/sqrt(6)
    const float PW2 = 1.2247448713915890f;    // sqrt(1.5)

    // cross(v,v) == 0 -> layer 1 collapses to (t0+t1)*C01 * s * v
    const float k1 = (tp1_w[0] + tp1_w[1]) * C01;
    float la[3], lbc[3];
    la[0] = PW2 * tp2_w[0] * C01;  lbc[0] = PW2 * tp2_w[1] * C11;
    la[1] = PW2 * tp3_w[0] * C01;  lbc[1] = PW2 * tp3_w[1] * C11;
    la[2] = PW2 * gate_w[0] * C01; lbc[2] = PW2 * gate_w[1] * C11;

    float lw[9], fw[9], lbv[3], fbv[3];
#pragma unroll
    for (int i = 0; i < 9; ++i) { lw[i] = lin_w[i]; fw[i] = fc_w[i]; }
#pragma unroll
    for (int i = 0; i < 3; ++i) { lbv[i] = lin_b[i]; fbv[i] = fc_b[i]; }

    const long long i0 = chunk0 + (long long)tid * NPT;

    float px[NPT], py[NPT], pz[NPT];
    int zi[NPT], bi[NPT];

    if (i0 + NPT <= (long long)n) {
        // 48B contiguous per lane: 3x float4 + int4 + int4, fully coalesced
        const float4* p4 = (const float4*)(pos + i0 * 3);
        float4 q0 = p4[0], q1 = p4[1], q2 = p4[2];
        px[0]=q0.x; py[0]=q0.y; pz[0]=q0.z;
        px[1]=q0.w; py[1]=q1.x; pz[1]=q1.y;
        px[2]=q1.z; py[2]=q1.w; pz[2]=q2.x;
        px[3]=q2.y; py[3]=q2.z; pz[3]=q2.w;
        int4 z4 = *(const int4*)(z + i0);
        zi[0]=z4.x; zi[1]=z4.y; zi[2]=z4.z; zi[3]=z4.w;
        int4 b4 = *(const int4*)(batch + i0);
        bi[0]=b4.x; bi[1]=b4.y; bi[2]=b4.z; bi[3]=b4.w;
    } else {
#pragma unroll
        for (int k = 0; k < NPT; ++k) {
            long long i = i0 + k;
            if (i < (long long)n) {
                px[k]=pos[i*3]; py[k]=pos[i*3+1]; pz[k]=pos[i*3+2];
                zi[k]=z[i]; bi[k]=batch[i];
            } else { px[k]=0.f; py[k]=0.f; pz[k]=0.f; zi[k]=0; bi[k]=-1; }
        }
    }

    auto flush = [&](int bidx, float x, float y, float zz) {
        int bl = bidx - bfirst;
        if (bl < TBL) {
            atomicAdd(&acc[bl*3+0], x);
            atomicAdd(&acc[bl*3+1], y);
            atomicAdd(&acc[bl*3+2], zz);
        } else {
            atomicAdd(&out[(long long)bidx*3+0], x);
            atomicAdd(&out[(long long)bidx*3+1], y);
            atomicAdd(&out[(long long)bidx*3+2], zz);
        }
    };

    float rx = 0.f, ry = 0.f, rz = 0.f;
    int rb = -1;

#pragma unroll
    for (int k = 0; k < NPT; ++k) {
        if (bi[k] < 0) continue;
        float s  = embed[zi[k]];
        float vx = lw[0]*px[k] + lw[1]*py[k] + lw[2]*pz[k] + lbv[0];
        float vy = lw[3]*px[k] + lw[4]*py[k] + lw[5]*pz[k] + lbv[1];
        float vz = lw[6]*px[k] + lw[7]*py[k] + lw[8]*pz[k] + lbv[2];

        float ks = k1 * s;
        float ox = ks * vx, oy = ks * vy, oz = ks * vz;

#pragma unroll
        for (int l = 0; l < 3; ++l) {
            float cx = oy*vz - oz*vy;
            float cy = oz*vx - ox*vz;
            float cz = ox*vy - oy*vx;
            float as_ = la[l] * s;
            float nx = as_*ox + lbc[l]*cx;
            float ny = as_*oy + lbc[l]*cy;
            float nz = as_*oz + lbc[l]*cz;
            ox = nx; oy = ny; oz = nz;
        }

        float yx = fw[0]*ox + fw[1]*oy + fw[2]*oz + fbv[0];
        float yy = fw[3]*ox + fw[4]*oy + fw[5]*oz + fbv[1];
        float yz = fw[6]*ox + fw[7]*oy + fw[8]*oz + fbv[2];

        if (bi[k] == rb) { rx += yx; ry += yy; rz += yz; }
        else {
            if (rb >= 0) flush(rb, rx, ry, rz);
            rb = bi[k]; rx = yx; ry = yy; rz = yz;
        }
    }
    if (rb >= 0) flush(rb, rx, ry, rz);

    __syncthreads();

    // drain LDS table -> global atomics (skip untouched entries)
    for (int e = tid; e < TBL; e += BLOCK) {
        float vx = acc[e*3+0], vy = acc[e*3+1], vz = acc[e*3+2];
        if (vx != 0.f || vy != 0.f || vz != 0.f) {
            long long g = (long long)(bfirst + e);
            atomicAdd(&out[g*3+0], vx);
            atomicAdd(&out[g*3+1], vy);
            atomicAdd(&out[g*3+2], vz);
        }
    }
}

extern "C" void kernel_launch(void* const* d_in, const int* in_sizes, int n_in,
                              void* d_out, int out_size, void* d_ws, size_t ws_size,
                              hipStream_t stream) {
    const int*   z     = (const int*)  d_in[0];
    const float* pos   = (const float*)d_in[1];
    const int*   batch = (const int*)  d_in[2];
    const float* embed = (const float*)d_in[3];
    const float* lin_w = (const float*)d_in[4];
    const float* lin_b = (const float*)d_in[5];
    const float* tp1_w = (const float*)d_in[6];
    const float* tp2_w = (const float*)d_in[7];
    const float* tp3_w = (const float*)d_in[8];
    const float* gate_w= (const float*)d_in[9];
    const float* fc_w  = (const float*)d_in[10];
    const float* fc_b  = (const float*)d_in[11];
    float* out = (float*)d_out;

    int n = in_sizes[0];

    // harness poisons d_out with 0xAA and never re-poisons between replays:
    // zero it every launch (memset node is graph-capture safe)
    hipMemsetAsync(d_out, 0, (size_t)out_size * sizeof(float), stream);

    int nblocks = (n + CHUNK - 1) / CHUNK;
    e3nn_fused<<<nblocks, BLOCK, 0, stream>>>(
        z, pos, batch, embed, lin_w, lin_b,
        tp1_w, tp2_w, tp3_w, gate_w, fc_w, fc_b, out, n);
}

// Round 2
// 32.214 us; speedup vs baseline: 1.3768x; 1.3768x over previous
//
#include <hip/hip_runtime.h>

#define BLOCK 256
#define NPT 8                     // nodes per thread
#define CHUNK (BLOCK * NPT)       // 2048 nodes per block

__global__ __launch_bounds__(BLOCK) void e3nn_fused(
    const int* __restrict__ z, const float* __restrict__ pos,
    const int* __restrict__ batch,
    const float* __restrict__ embed,
    const float* __restrict__ lin_w, const float* __restrict__ lin_b,
    const float* __restrict__ tp1_w, const float* __restrict__ tp2_w,
    const float* __restrict__ tp3_w, const float* __restrict__ gate_w,
    const float* __restrict__ fc_w, const float* __restrict__ fc_b,
    float* __restrict__ out, int n)
{
    const int tid = threadIdx.x;
    const int lane = tid & 63;
    const long long i0 = (long long)blockIdx.x * CHUNK + (long long)tid * NPT;

    float px[NPT], py[NPT], pz[NPT];
    int zi[NPT], bi[NPT];

    if (i0 + NPT <= (long long)n) {
        // 96B pos + 32B z + 32B batch per lane, all contiguous vector loads
        const float4* p4 = (const float4*)(pos + i0 * 3);
        float4 q0 = p4[0], q1 = p4[1], q2 = p4[2], q3 = p4[3], q4 = p4[4], q5 = p4[5];
        px[0]=q0.x; py[0]=q0.y; pz[0]=q0.z;
        px[1]=q0.w; py[1]=q1.x; pz[1]=q1.y;
        px[2]=q1.z; py[2]=q1.w; pz[2]=q2.x;
        px[3]=q2.y; py[3]=q2.z; pz[3]=q2.w;
        px[4]=q3.x; py[4]=q3.y; pz[4]=q3.z;
        px[5]=q3.w; py[5]=q4.x; pz[5]=q4.y;
        px[6]=q4.z; py[6]=q4.w; pz[6]=q5.x;
        px[7]=q5.y; py[7]=q5.z; pz[7]=q5.w;
        int4 za = *(const int4*)(z + i0), zb = *(const int4*)(z + i0 + 4);
        zi[0]=za.x; zi[1]=za.y; zi[2]=za.z; zi[3]=za.w;
        zi[4]=zb.x; zi[5]=zb.y; zi[6]=zb.z; zi[7]=zb.w;
        int4 ba = *(const int4*)(batch + i0), bb = *(const int4*)(batch + i0 + 4);
        bi[0]=ba.x; bi[1]=ba.y; bi[2]=ba.z; bi[3]=ba.w;
        bi[4]=bb.x; bi[5]=bb.y; bi[6]=bb.z; bi[7]=bb.w;
    } else {
#pragma unroll
        for (int k = 0; k < NPT; ++k) {
            long long i = i0 + k;
            if (i < (long long)n) {
                px[k]=pos[i*3]; py[k]=pos[i*3+1]; pz[k]=pos[i*3+2];
                zi[k]=z[i]; bi[k]=batch[i];
            } else { px[k]=0.f; py[k]=0.f; pz[k]=0.f; zi[k]=0; bi[k]=-1; }
        }
    }

    // Wigner / path-weight constants
    const float C01 = 0.57735026918962576f;   // 1/sqrt(3)
    const float C11 = 0.40824829046386302f;   // 1/sqrt(6)
    const float PW2 = 1.2247448713915890f;    // sqrt(1.5)

    // cross(v,v) == 0 -> layer 1 collapses to (t0+t1)*C01 * s * v
    const float k1 = (tp1_w[0] + tp1_w[1]) * C01;
    float la[3], lbc[3];
    la[0] = PW2 * tp2_w[0] * C01;  lbc[0] = PW2 * tp2_w[1] * C11;
    la[1] = PW2 * tp3_w[0] * C01;  lbc[1] = PW2 * tp3_w[1] * C11;
    la[2] = PW2 * gate_w[0] * C01; lbc[2] = PW2 * gate_w[1] * C11;

    float lw[9], fw[9], lbv[3], fbv[3];
#pragma unroll
    for (int i = 0; i < 9; ++i) { lw[i] = lin_w[i]; fw[i] = fc_w[i]; }
#pragma unroll
    for (int i = 0; i < 3; ++i) { lbv[i] = lin_b[i]; fbv[i] = fc_b[i]; }

    // per-thread run-length compression over sorted batch ids
    float rx = 0.f, ry = 0.f, rz = 0.f;
    int rb = -1;

#pragma unroll
    for (int k = 0; k < NPT; ++k) {
        if (bi[k] < 0) continue;
        float s  = embed[zi[k]];
        float vx = lw[0]*px[k] + lw[1]*py[k] + lw[2]*pz[k] + lbv[0];
        float vy = lw[3]*px[k] + lw[4]*py[k] + lw[5]*pz[k] + lbv[1];
        float vz = lw[6]*px[k] + lw[7]*py[k] + lw[8]*pz[k] + lbv[2];

        float ks = k1 * s;
        float ox = ks * vx, oy = ks * vy, oz = ks * vz;

#pragma unroll
        for (int l = 0; l < 3; ++l) {
            float cx = oy*vz - oz*vy;
            float cy = oz*vx - ox*vz;
            float cz = ox*vy - oy*vx;
            float as_ = la[l] * s;
            ox = as_*ox + lbc[l]*cx;
            oy = as_*oy + lbc[l]*cy;
            oz = as_*oz + lbc[l]*cz;
        }

        float yx = fw[0]*ox + fw[1]*oy + fw[2]*oz + fbv[0];
        float yy = fw[3]*ox + fw[4]*oy + fw[5]*oz + fbv[1];
        float yz = fw[6]*ox + fw[7]*oy + fw[8]*oz + fbv[2];

        if (bi[k] == rb) { rx += yx; ry += yy; rz += yz; }
        else {
            if (rb >= 0) {  // earlier run in this lane (rare: boundary inside lane)
                atomicAdd(&out[(long long)rb*3+0], rx);
                atomicAdd(&out[(long long)rb*3+1], ry);
                atomicAdd(&out[(long long)rb*3+2], rz);
            }
            rb = bi[k]; rx = yx; ry = yy; rz = yz;
        }
    }

    // wave-level segmented suffix reduction over each lane's LAST run.
    // Keys are non-decreasing across lanes; after log2(64) steps the head
    // lane of each equal-key run holds the full run sum.
#pragma unroll
    for (int off = 1; off < 64; off <<= 1) {
        int   ob = __shfl_down(rb, off);
        float ox = __shfl_down(rx, off);
        float oy = __shfl_down(ry, off);
        float oz = __shfl_down(rz, off);
        if ((lane + off) < 64 && ob == rb) { rx += ox; ry += oy; rz += oz; }
    }
    int pb = __shfl_up(rb, 1);
    bool head = (lane == 0) || (pb != rb);
    if (rb >= 0 && head) {
        atomicAdd(&out[(long long)rb*3+0], rx);
        atomicAdd(&out[(long long)rb*3+1], ry);
        atomicAdd(&out[(long long)rb*3+2], rz);
    }
}

extern "C" void kernel_launch(void* const* d_in, const int* in_sizes, int n_in,
                              void* d_out, int out_size, void* d_ws, size_t ws_size,
                              hipStream_t stream) {
    const int*   z     = (const int*)  d_in[0];
    const float* pos   = (const float*)d_in[1];
    const int*   batch = (const int*)  d_in[2];
    const float* embed = (const float*)d_in[3];
    const float* lin_w = (const float*)d_in[4];
    const float* lin_b = (const float*)d_in[5];
    const float* tp1_w = (const float*)d_in[6];
    const float* tp2_w = (const float*)d_in[7];
    const float* tp3_w = (const float*)d_in[8];
    const float* gate_w= (const float*)d_in[9];
    const float* fc_w  = (const float*)d_in[10];
    const float* fc_b  = (const float*)d_in[11];
    float* out = (float*)d_out;

    int n = in_sizes[0];

    // harness poisons d_out with 0xAA and never re-poisons between replays:
    // zero it every launch (memset node is graph-capture safe)
    hipMemsetAsync(d_out, 0, (size_t)out_size * sizeof(float), stream);

    int nblocks = (n + CHUNK - 1) / CHUNK;
    e3nn_fused<<<nblocks, BLOCK, 0, stream>>>(
        z, pos, batch, embed, lin_w, lin_b,
        tp1_w, tp2_w, tp3_w, gate_w, fc_w, fc_b, out, n);
}